// Round 1
// baseline (87.861 us; speedup 1.0000x reference)
//
#include <hip/hip_runtime.h>
#include <hip/hip_bf16.h>

// Problem constants (fixed by the reference):
// x: [4, 4096, 4096] f32, W1: [48, 4096] f32, W2: [48, 48] f32
// out: [4, 4, 4096, 12] f32  (C, B, T, L/C)
#define DDIM 4096
#define LTOT 48
#define BQ 4
#define TT 4096

typedef __attribute__((ext_vector_type(4))) float f32x4;
typedef __attribute__((ext_vector_type(8))) short bf16x8;

__device__ __forceinline__ short f2bf(float f) {
    union { float f; unsigned u; } v; v.f = f;
    unsigned r = v.u + 0x7fffu + ((v.u >> 16) & 1u);   // RNE; data is normal floats
    return (short)(r >> 16);
}

// ---- kernel 0: W1 fp32 -> bf16 into workspace (48*4096 = 196608 elems) ----
__global__ void w1cvt_kernel(const float* __restrict__ w1, ushort* __restrict__ w1b) {
    int i = blockIdx.x * 256 + threadIdx.x;          // grid sized exactly
    union { float f; unsigned u; } v; v.f = w1[i];
    unsigned r = v.u + 0x7fffu + ((v.u >> 16) & 1u);
    w1b[i] = (ushort)(r >> 16);
}

// ---- fused: sumsq + x@W1^T (bf16 MFMA, K-split over 4 waves) + rms-scale
//      + exact GELU + @W2^T + transposed store ----
__global__ __launch_bounds__(256) void fused_kernel(
        const float* __restrict__ x,
        const ushort* __restrict__ w1b,
        const float* __restrict__ w2,
        float* __restrict__ out) {
    __shared__ float dots[4][16][48];   // per-wave K-split partial dots
    __shared__ float ssw[4][16];        // per-wave partial sumsq
    __shared__ float scl[16];           // per-row rms scale
    __shared__ float gbuf[16][48];      // gelu(h)
    __shared__ float w2s[LTOT * LTOT];  // W2 staged

    const int tid  = threadIdx.x;
    const int wave = tid >> 6;
    const int lane = tid & 63;
    const int rl   = lane & 15;   // row-in-tile for A, out-col for B
    const int kg   = lane >> 2 >> 2; // lane>>4: k-group 0..3

    const int row0 = blockIdx.x * 16;

    // A: lane covers x row (row0+rl), k = wave*1024 + kg*8 + [0..7] + 32*step
    const float*  xp = x   + (size_t)(row0 + rl) * DDIM + wave * 1024 + kg * 8;
    // B: lane covers W1 row (ntile*16 + rl), same k slots
    const ushort* bp = w1b + (size_t)rl * DDIM          + wave * 1024 + kg * 8;

    f32x4 acc0 = {0.f, 0.f, 0.f, 0.f};
    f32x4 acc1 = acc0, acc2 = acc0;
    float ss = 0.f;

    #pragma unroll 4
    for (int s = 0; s < 32; ++s) {
        f32x4 a0 = *(const f32x4*)(xp);
        f32x4 a1 = *(const f32x4*)(xp + 4);
        xp += 32;
        bf16x8 b0 = *(const bf16x8*)(bp);
        bf16x8 b1 = *(const bf16x8*)(bp + 16 * DDIM);
        bf16x8 b2 = *(const bf16x8*)(bp + 32 * DDIM);
        bp += 32;

        ss = fmaf(a0.x, a0.x, ss); ss = fmaf(a0.y, a0.y, ss);
        ss = fmaf(a0.z, a0.z, ss); ss = fmaf(a0.w, a0.w, ss);
        ss = fmaf(a1.x, a1.x, ss); ss = fmaf(a1.y, a1.y, ss);
        ss = fmaf(a1.z, a1.z, ss); ss = fmaf(a1.w, a1.w, ss);

        bf16x8 af;
        af[0] = f2bf(a0.x); af[1] = f2bf(a0.y); af[2] = f2bf(a0.z); af[3] = f2bf(a0.w);
        af[4] = f2bf(a1.x); af[5] = f2bf(a1.y); af[6] = f2bf(a1.z); af[7] = f2bf(a1.w);

        acc0 = __builtin_amdgcn_mfma_f32_16x16x32_bf16(af, b0, acc0, 0, 0, 0);
        acc1 = __builtin_amdgcn_mfma_f32_16x16x32_bf16(af, b1, acc1, 0, 0, 0);
        acc2 = __builtin_amdgcn_mfma_f32_16x16x32_bf16(af, b2, acc2, 0, 0, 0);
    }

    // ---- wave-local reductions into LDS ----
    ss += __shfl_xor(ss, 16);
    ss += __shfl_xor(ss, 32);
    if (lane < 16) ssw[wave][lane] = ss;

    // C layout: col = lane&15 (= out l index), row = kg*4 + reg
    #pragma unroll
    for (int i = 0; i < 4; ++i) {
        dots[wave][kg * 4 + i][ 0 + rl] = acc0[i];
        dots[wave][kg * 4 + i][16 + rl] = acc1[i];
        dots[wave][kg * 4 + i][32 + rl] = acc2[i];
    }

    // stage W2 while we're at it
    for (int i = tid; i < LTOT * LTOT; i += 256) w2s[i] = w2[i];
    __syncthreads();

    if (tid < 16) {
        float st = ssw[0][tid] + ssw[1][tid] + ssw[2][tid] + ssw[3][tid];
        scl[tid] = rsqrtf(st * (1.0f / (float)DDIM) + 1e-5f);
    }
    __syncthreads();

    // combine K-split partials, scale, exact gelu
    #pragma unroll
    for (int i = 0; i < 3; ++i) {
        int v = tid + i * 256;                    // 0..767
        int row = v / 48, col = v - row * 48;
        float dsum = dots[0][row][col] + dots[1][row][col]
                   + dots[2][row][col] + dots[3][row][col];
        float h = dsum * scl[row];
        gbuf[row][col] = h * 0.5f * (1.0f + erff(h * 0.70710678118654752f));
    }
    __syncthreads();

    // dw = g @ W2^T, scatter-store into [C,B,T,12]
    #pragma unroll
    for (int i = 0; i < 3; ++i) {
        int v = tid + i * 256;
        int row = v / 48, l = v - row * 48;
        float sacc = 0.f;
        #pragma unroll
        for (int k = 0; k < LTOT; ++k)
            sacc = fmaf(gbuf[row][k], w2s[l * LTOT + k], sacc);
        int rg = row0 + row;
        int b  = rg >> 12;          // / 4096
        int t  = rg & 4095;
        int c  = l / 12, j = l - c * 12;
        out[(((size_t)(c * BQ + b) * TT + t) * 12) + j] = sacc;
    }
}

extern "C" void kernel_launch(void* const* d_in, const int* in_sizes, int n_in,
                              void* d_out, int out_size, void* d_ws, size_t ws_size,
                              hipStream_t stream) {
    const float* x  = (const float*)d_in[0];
    const float* W1 = (const float*)d_in[1];
    const float* W2 = (const float*)d_in[2];
    float* out = (float*)d_out;
    ushort* w1b = (ushort*)d_ws;   // 384 KB scratch

    w1cvt_kernel<<<(LTOT * DDIM) / 256, 256, 0, stream>>>(W1, w1b);
    fused_kernel<<<(BQ * TT) / 16, 256, 0, stream>>>(x, w1b, W2, out);
}

// Round 2
// 70.895 us; speedup vs baseline: 1.2393x; 1.2393x over previous
//
#include <hip/hip_runtime.h>
#include <hip/hip_bf16.h>

// x: [4, 4096, 4096] f32, W1: [48, 4096] f32, W2: [48, 48] f32
// out: [4, 4, 4096, 12] f32  (C, B, T, L/C)
#define DDIM 4096
#define LTOT 48
#define BQ 4
#define TT 4096

typedef __attribute__((ext_vector_type(4))) float f32x4;
typedef __attribute__((ext_vector_type(8))) short bf16x8;

__device__ __forceinline__ void gload_lds16(const void* g, void* l) {
    __builtin_amdgcn_global_load_lds(
        (const __attribute__((address_space(1))) void*)g,
        (__attribute__((address_space(3))) void*)l, 16, 0, 0);
}

__device__ __forceinline__ unsigned cvt_pk(float x, float y) {
    union { __hip_bfloat162 h; unsigned u; } c;
    c.h = __float22bfloat162_rn(make_float2(x, y));
    return c.u;
}

// ---- kernel 0: W1 fp32 -> bf16 into workspace ----
__global__ void w1cvt_kernel(const float* __restrict__ w1, ushort* __restrict__ w1b) {
    int i = blockIdx.x * 256 + threadIdx.x;
    union { float f; unsigned u; } v; v.f = w1[i];
    unsigned r = v.u + 0x7fffu + ((v.u >> 16) & 1u);
    w1b[i] = (ushort)(r >> 16);
}

// ---- fused: async-staged sumsq + x@W1^T + rms + gelu + @W2^T + store ----
__global__ __launch_bounds__(256, 4) void fused_kernel(
        const float* __restrict__ x,
        const ushort* __restrict__ w1b,
        const float* __restrict__ w2,
        float* __restrict__ out) {
    // staging: 4 waves x 2 buffers x 4096B (16 rows x 64 f32, XOR-swizzled 16B blocks)
    __shared__ __align__(1024) char smem[32768];
    __shared__ float ssw[4][16];
    __shared__ float scl[16];

    const int tid  = threadIdx.x;
    const int wave = tid >> 6;
    const int lane = tid & 63;
    const int rl   = lane & 15;   // A-row / B-row / C-col
    const int kg   = lane >> 4;   // k-group 0..3
    const int row0 = blockIdx.x * 16;
    const int kw   = wave * 1024; // per-wave K range

    char* wbase = smem + wave * 8192;

    // ds_read byte offsets within one buffer for (half h, piece p):
    // global 16B-block g = h*8 + kg*2 + p lives at LDS block g ^ rl of row rl
    int dso[2][2];
    #pragma unroll
    for (int h = 0; h < 2; ++h)
        #pragma unroll
        for (int p = 0; p < 2; ++p)
            dso[h][p] = rl * 256 + (((h * 8 + kg * 2 + p) ^ rl) << 4);

    // stage K-step t into buffer t&1 (4 x 1KB global_load_lds, linear dest,
    // inverse-swizzled per-lane global source)
    auto stage = [&](int t) {
        const int kb = kw + t * 64;
        char* lb = wbase + (t & 1) * 4096;
        #pragma unroll
        for (int i = 0; i < 4; ++i) {
            int rloc = i * 4 + kg;           // row this lane's 16B lands in
            int blkg = rl ^ rloc;            // source block (inverse swizzle)
            const float* src = x + (size_t)(row0 + rloc) * DDIM + kb + blkg * 4;
            gload_lds16(src, lb + i * 1024);
        }
    };

    // B fragments for K-step s (6 x 16B, L2-resident)
    auto loadB = [&](int s, bf16x8 (&bl)[6]) {
        const ushort* bp = w1b + (size_t)rl * DDIM + kw + s * 64 + kg * 8;
        #pragma unroll
        for (int n = 0; n < 3; ++n)
            #pragma unroll
            for (int h = 0; h < 2; ++h)
                bl[n * 2 + h] = *(const bf16x8*)(bp + n * 16 * DDIM + h * 32);
    };

    float ss = 0.f;
    f32x4 acc[3] = {{0.f,0.f,0.f,0.f},{0.f,0.f,0.f,0.f},{0.f,0.f,0.f,0.f}};
    bf16x8 bA[6], bB[6];

    // prologue: two buffers in flight + first B
    stage(0); stage(1); loadB(0, bA);

    auto body = [&](int s, bf16x8 (&bu)[6], bf16x8 (&bl)[6]) {
        // stage(s) done when <=4 vmem outstanding (stage(s+1) stays in flight)
        asm volatile("s_waitcnt vmcnt(4)" ::: "memory");
        char* lb = wbase + (s & 1) * 4096;
        f32x4 a[2][2];
        #pragma unroll
        for (int h = 0; h < 2; ++h)
            #pragma unroll
            for (int p = 0; p < 2; ++p)
                a[h][p] = *(const f32x4*)(lb + dso[h][p]);
        if (s < 15) loadB(s + 1, bl);   // B one step ahead (reg double-buffer)
        #pragma unroll
        for (int h = 0; h < 2; ++h) {
            f32x4 a0 = a[h][0], a1 = a[h][1];
            ss = fmaf(a0.x, a0.x, ss); ss = fmaf(a0.y, a0.y, ss);
            ss = fmaf(a0.z, a0.z, ss); ss = fmaf(a0.w, a0.w, ss);
            ss = fmaf(a1.x, a1.x, ss); ss = fmaf(a1.y, a1.y, ss);
            ss = fmaf(a1.z, a1.z, ss); ss = fmaf(a1.w, a1.w, ss);
            union { bf16x8 v; unsigned u[4]; } af;
            af.u[0] = cvt_pk(a0.x, a0.y); af.u[1] = cvt_pk(a0.z, a0.w);
            af.u[2] = cvt_pk(a1.x, a1.y); af.u[3] = cvt_pk(a1.z, a1.w);
            #pragma unroll
            for (int n = 0; n < 3; ++n)
                acc[n] = __builtin_amdgcn_mfma_f32_16x16x32_bf16(
                             af.v, bu[n * 2 + h], acc[n], 0, 0, 0);
        }
        // ds_reads of this buffer must land before we overwrite it
        asm volatile("s_waitcnt lgkmcnt(0)" ::: "memory");
        if (s < 14) stage(s + 2);
    };

    for (int sp = 0; sp < 8; ++sp) {
        body(2 * sp,     bA, bB);
        body(2 * sp + 1, bB, bA);
    }

    // ---- reductions ----
    ss += __shfl_xor(ss, 16);
    ss += __shfl_xor(ss, 32);
    if (lane < 16) ssw[wave][lane] = ss;
    __syncthreads();   // all waves done with staging LDS -> safe to overlay

    float* dots = (float*)smem;            // [4][16][48] f32 = 12288 B
    float* gbuf = (float*)(smem + 12288);  // [16][48]    f32 =  3072 B
    float* w2s  = (float*)(smem + 15360);  // [48*48]     f32 =  9216 B

    #pragma unroll
    for (int n = 0; n < 3; ++n)
        #pragma unroll
        for (int i = 0; i < 4; ++i)
            dots[(wave * 16 + kg * 4 + i) * 48 + n * 16 + rl] = acc[n][i];
    for (int i = tid; i < LTOT * LTOT; i += 256) w2s[i] = w2[i];
    __syncthreads();

    if (tid < 16) {
        float st = ssw[0][tid] + ssw[1][tid] + ssw[2][tid] + ssw[3][tid];
        scl[tid] = rsqrtf(st * (1.0f / (float)DDIM) + 1e-5f);
    }
    __syncthreads();

    #pragma unroll
    for (int i = 0; i < 3; ++i) {
        int v = tid + i * 256;
        int row = v / 48, col = v - row * 48;
        float d = dots[(0 * 16 + row) * 48 + col] + dots[(1 * 16 + row) * 48 + col]
                + dots[(2 * 16 + row) * 48 + col] + dots[(3 * 16 + row) * 48 + col];
        float h = d * scl[row];
        gbuf[row * 48 + col] = h * 0.5f * (1.0f + erff(h * 0.70710678118654752f));
    }
    __syncthreads();

    #pragma unroll
    for (int i = 0; i < 3; ++i) {
        int v = tid + i * 256;
        int row = v / 48, l = v - row * 48;
        float sacc = 0.f;
        #pragma unroll
        for (int k = 0; k < LTOT; ++k)
            sacc = fmaf(gbuf[row * 48 + k], w2s[l * LTOT + k], sacc);
        int rg = row0 + row;
        int b  = rg >> 12;
        int t  = rg & 4095;
        int c  = l / 12, j = l - c * 12;
        out[(((size_t)(c * BQ + b) * TT + t) * 12) + j] = sacc;
    }
}

extern "C" void kernel_launch(void* const* d_in, const int* in_sizes, int n_in,
                              void* d_out, int out_size, void* d_ws, size_t ws_size,
                              hipStream_t stream) {
    const float* x  = (const float*)d_in[0];
    const float* W1 = (const float*)d_in[1];
    const float* W2 = (const float*)d_in[2];
    float* out = (float*)d_out;
    ushort* w1b = (ushort*)d_ws;

    w1cvt_kernel<<<(LTOT * DDIM) / 256, 256, 0, stream>>>(W1, w1b);
    fused_kernel<<<(BQ * TT) / 16, 256, 0, stream>>>(x, w1b, W2, out);
}